// Round 2
// baseline (1026.342 us; speedup 1.0000x reference)
//
#include <hip/hip_runtime.h>
#include <math.h>

// Problem constants: N=20000, E=160000, D=768, H=256, C=10
// Outputs (fp32, concatenated): logits [N,10], node_features [N,513], edge_pairs [E,1026]
//
// Structure (this round): edge_pairs is never gathered — each aggregate scatters its
// freshly-computed 256-col slab directly into the pair rows via CSR-by-src / CSR-by-dst
// (with original edge ids). Classifier is fused into the aggregates as partial-logit sums.

typedef __attribute__((ext_vector_type(8))) short short8;
typedef __attribute__((ext_vector_type(4))) float f32x4;
typedef __attribute__((ext_vector_type(2))) float f32x2;

static __device__ __forceinline__ unsigned short f2bf(float f) {
    unsigned u = __float_as_uint(f);
    u += 0x7fffu + ((u >> 16) & 1u);  // RNE
    return (unsigned short)(u >> 16);
}
static __device__ __forceinline__ float bf2f(unsigned short h) {
    return __uint_as_float((unsigned)h << 16);
}

// ---------------- CSR build (both directions) ----------------

__global__ void k_hist2(const int* __restrict__ src, const int* __restrict__ dst,
                        int* __restrict__ deg_d, int* __restrict__ deg_s,
                        int* __restrict__ rank_d, int* __restrict__ rank_s, int e) {
    int i = blockIdx.x * blockDim.x + threadIdx.x;
    if (i < e) {
        rank_d[i] = atomicAdd(&deg_d[dst[i]], 1);
        rank_s[i] = atomicAdd(&deg_s[src[i]], 1);
    }
}

// single-block, thread-coarsened exclusive scan of two arrays.
__global__ __launch_bounds__(1024) void k_scan2(const int* __restrict__ degA, int* __restrict__ offA,
                                                const int* __restrict__ degB, int* __restrict__ offB,
                                                int n, int total) {
    __shared__ int part[1024];
    const int t = threadIdx.x;
    const int per = (n + 1023) >> 10;
    const int s0 = t * per;
    int s1 = s0 + per; if (s1 > n) s1 = n;
    for (int pass = 0; pass < 2; pass++) {
        const int* __restrict__ deg = pass ? degB : degA;
        int* __restrict__ off = pass ? offB : offA;
        int s = 0;
        for (int i = s0; i < s1; i++) s += deg[i];
        part[t] = s;
        __syncthreads();
        int x = s;
        for (int ofs = 1; ofs < 1024; ofs <<= 1) {
            int add = (t >= ofs) ? part[t - ofs] : 0;
            __syncthreads();
            x += add;
            part[t] = x;
            __syncthreads();
        }
        int run = x - s;  // exclusive prefix of this chunk
        for (int i = s0; i < s1; i++) { off[i] = run; run += deg[i]; }
        if (t == 0) off[n] = total;
        __syncthreads();
    }
}

__global__ void k_scatter2(const int* __restrict__ src, const int* __restrict__ dst,
                           const int* __restrict__ deg_d,
                           const int* __restrict__ off_d, const int* __restrict__ off_s,
                           const int* __restrict__ rank_d, const int* __restrict__ rank_s,
                           int* __restrict__ csrD_src, float* __restrict__ csrD_w,
                           int* __restrict__ csrD_eid, int* __restrict__ csrS_eid, int e) {
    int i = blockIdx.x * blockDim.x + threadIdx.x;
    if (i < e) {
        const int d = dst[i], s = src[i];
        const int posd = off_d[d] + rank_d[i];
        csrD_src[posd] = s;
        // norm = dinv[s]*dinv[d], dinv from IN-degree (+1 self-loop), matching reference
        csrD_w[posd] = rsqrtf((float)(deg_d[s] + 1) * (float)(deg_d[d] + 1));
        csrD_eid[posd] = i;
        csrS_eid[off_s[s] + rank_s[i]] = i;
    }
}

// ---------------- fp32 -> bf16 hi/lo split ----------------

__global__ void k_split_x(const float* __restrict__ x, unsigned short* __restrict__ hi,
                          unsigned short* __restrict__ lo, int total4) {
    const int stride = gridDim.x * blockDim.x;
    for (int i = blockIdx.x * blockDim.x + threadIdx.x; i < total4; i += stride) {
        const float4 v = ((const float4*)x)[i];
        const unsigned short h0 = f2bf(v.x), h1 = f2bf(v.y), h2 = f2bf(v.z), h3 = f2bf(v.w);
        const unsigned short l0 = f2bf(v.x - bf2f(h0)), l1 = f2bf(v.y - bf2f(h1)),
                             l2 = f2bf(v.z - bf2f(h2)), l3 = f2bf(v.w - bf2f(h3));
        *(ushort4*)(hi + 4 * (size_t)i) = make_ushort4(h0, h1, h2, h3);
        *(ushort4*)(lo + 4 * (size_t)i) = make_ushort4(l0, l1, l2, l3);
    }
}

// W [K,N] fp32 -> Wt [N,K] bf16 hi/lo (transposed so MFMA B-frags are contiguous-K)
__global__ void k_split_wt(const float* __restrict__ W, unsigned short* __restrict__ wthi,
                           unsigned short* __restrict__ wtlo, int K, int N) {
    int idx = blockIdx.x * blockDim.x + threadIdx.x;
    if (idx >= K * N) return;
    const int k = idx / N, nn = idx - k * N;
    const float v = W[idx];
    const unsigned short h = f2bf(v);
    wthi[(size_t)nn * K + k] = h;
    wtlo[(size_t)nn * K + k] = f2bf(v - bf2f(h));
}

// ---------------- split-bf16 MFMA GEMM: C[M,256] = (Ahi+Alo)[M,K] @ (Bhi+Blo)^T[K,256] ----------------
// BM=BN=128, BK=32, 256 threads (2x2 waves, each 64x64 via 4x4 16x16x32 fragments).
// 3-term split: hi*hi + hi*lo + lo*hi (lo*lo ~ 2^-18 rel, dropped).
__global__ __launch_bounds__(256) void k_gemm_mfma(
    const unsigned short* __restrict__ Ahi, const unsigned short* __restrict__ Alo,
    const unsigned short* __restrict__ Bhi, const unsigned short* __restrict__ Blo,
    float* __restrict__ C, int M, int K)
{
    __shared__ short As_hi[128 * 32], As_lo[128 * 32], Bs_hi[128 * 32], Bs_lo[128 * 32];
    const int tid = threadIdx.x;
    const int m0 = blockIdx.y * 128, n0 = blockIdx.x * 128;
    const int lane = tid & 63;
    const int wr = (tid >> 7) & 1, wc = (tid >> 6) & 1;
    const int l15 = lane & 15, l16 = lane >> 4;

    f32x4 acc[4][4] = {};

    const int srow = tid >> 1;
    const int sc0 = (tid & 1) * 2;
    const bool aok = (m0 + srow) < M;
    const unsigned short* Ap  = Ahi + (size_t)(m0 + srow) * K;
    const unsigned short* Alp = Alo + (size_t)(m0 + srow) * K;
    const unsigned short* Bp  = Bhi + (size_t)(n0 + srow) * K;
    const unsigned short* Blp = Blo + (size_t)(n0 + srow) * K;
    const int sw0 = ((sc0 ^ ((srow >> 1) & 3)) << 3);
    const int sw1 = (((sc0 + 1) ^ ((srow >> 1) & 3)) << 3);
    const int sbase = srow * 32;

    for (int k0 = 0; k0 < K; k0 += 32) {
        short8 ah0 = {0,0,0,0,0,0,0,0}, ah1 = {0,0,0,0,0,0,0,0};
        short8 al0 = {0,0,0,0,0,0,0,0}, al1 = {0,0,0,0,0,0,0,0};
        if (aok) {
            ah0 = *(const short8*)(Ap  + k0 + sc0 * 8);
            ah1 = *(const short8*)(Ap  + k0 + sc0 * 8 + 8);
            al0 = *(const short8*)(Alp + k0 + sc0 * 8);
            al1 = *(const short8*)(Alp + k0 + sc0 * 8 + 8);
        }
        const short8 bh0 = *(const short8*)(Bp  + k0 + sc0 * 8);
        const short8 bh1 = *(const short8*)(Bp  + k0 + sc0 * 8 + 8);
        const short8 bl0 = *(const short8*)(Blp + k0 + sc0 * 8);
        const short8 bl1 = *(const short8*)(Blp + k0 + sc0 * 8 + 8);
        __syncthreads();
        *(short8*)&As_hi[sbase + sw0] = ah0;
        *(short8*)&As_hi[sbase + sw1] = ah1;
        *(short8*)&As_lo[sbase + sw0] = al0;
        *(short8*)&As_lo[sbase + sw1] = al1;
        *(short8*)&Bs_hi[sbase + sw0] = bh0;
        *(short8*)&Bs_hi[sbase + sw1] = bh1;
        *(short8*)&Bs_lo[sbase + sw0] = bl0;
        *(short8*)&Bs_lo[sbase + sw1] = bl1;
        __syncthreads();

        short8 afh[4], afl[4];
#pragma unroll
        for (int i = 0; i < 4; i++) {
            const int r = wr * 64 + i * 16 + l15;
            const int off = r * 32 + ((l16 ^ ((r >> 1) & 3)) << 3);
            afh[i] = *(const short8*)&As_hi[off];
            afl[i] = *(const short8*)&As_lo[off];
        }
#pragma unroll
        for (int j = 0; j < 4; j++) {
            const int r = wc * 64 + j * 16 + l15;
            const int off = r * 32 + ((l16 ^ ((r >> 1) & 3)) << 3);
            const short8 bfh = *(const short8*)&Bs_hi[off];
            const short8 bfl = *(const short8*)&Bs_lo[off];
#pragma unroll
            for (int i = 0; i < 4; i++) {
                acc[i][j] = __builtin_amdgcn_mfma_f32_16x16x32_bf16(afh[i], bfh, acc[i][j], 0, 0, 0);
                acc[i][j] = __builtin_amdgcn_mfma_f32_16x16x32_bf16(afh[i], bfl, acc[i][j], 0, 0, 0);
                acc[i][j] = __builtin_amdgcn_mfma_f32_16x16x32_bf16(afl[i], bfh, acc[i][j], 0, 0, 0);
            }
        }
    }

    // C/D layout (verified m89/m91): col = lane&15, row = (lane>>4)*4 + q
#pragma unroll
    for (int i = 0; i < 4; i++) {
#pragma unroll
        for (int q = 0; q < 4; q++) {
            const int m = m0 + wr * 64 + i * 16 + l16 * 4 + q;
            if (m < M) {
#pragma unroll
                for (int j = 0; j < 4; j++)
                    C[(size_t)m * 256 + n0 + wc * 64 + j * 16 + l15] = acc[i][j][q];
            }
        }
    }
}

// ---------------- aggregation (dim=256): wave per node ----------------
// h[v] = tanh(sum_nbr w*t[u] + (1/(deg+1))*t[v] + b)
// Writes: nf slab, pair-row slabs (src half via csrS, dst half via csrD), partial logits;
// optional bf16 hi/lo split out (layer1), optional fused W2 row-dot -> sv (layer2).
__global__ __launch_bounds__(256) void k_aggregate(
    const float* __restrict__ t, const float* __restrict__ bias,
    const int* __restrict__ deg_d,
    const int* __restrict__ offD, const int* __restrict__ csrD_src,
    const float* __restrict__ csrD_w, const int* __restrict__ csrD_eid,
    const int* __restrict__ offS, const int* __restrict__ csrS_eid,
    float* __restrict__ nf, float* __restrict__ pairs, int col0,
    unsigned short* __restrict__ hhi, unsigned short* __restrict__ hlo,
    const float* __restrict__ W2, float* __restrict__ sv,
    const float* __restrict__ Wc, float* __restrict__ pl, int accum, int n)
{
    const int v = blockIdx.x * 4 + (threadIdx.x >> 6);
    if (v >= n) return;
    const int lane = threadIdx.x & 63;
    const float dii = 1.0f / (float)(deg_d[v] + 1);
    const float4 tb = *(const float4*)(bias + lane * 4);
    const float4 a  = *(const float4*)(t + (size_t)v * 256 + lane * 4);
    float4 s4 = make_float4(dii * a.x, dii * a.y, dii * a.z, dii * a.w);
    const int d0 = offD[v], d1 = offD[v + 1];
    for (int idx = d0; idx < d1; idx++) {
        const int u = csrD_src[idx];
        const float w = csrD_w[idx];
        const float4 tv = *(const float4*)(t + (size_t)u * 256 + lane * 4);
        s4.x = fmaf(w, tv.x, s4.x);
        s4.y = fmaf(w, tv.y, s4.y);
        s4.z = fmaf(w, tv.z, s4.z);
        s4.w = fmaf(w, tv.w, s4.w);
    }
    float4 r;
    r.x = tanhf(s4.x + tb.x);
    r.y = tanhf(s4.y + tb.y);
    r.z = tanhf(s4.z + tb.z);
    r.w = tanhf(s4.w + tb.w);

    // nf slab (scalar dwords; rows only 4B-aligned)
    float* nfp = nf + (size_t)v * 513 + col0 + lane * 4;
    nfp[0] = r.x; nfp[1] = r.y; nfp[2] = r.z; nfp[3] = r.w;

    // pair rows, src half: byte base = eid*4104 + col0*4 + lane*16 -> 8B aligned
    const f32x2 rlo = {r.x, r.y}, rhi = {r.z, r.w};
    const int so0 = offS[v], so1 = offS[v + 1];
    for (int j = so0; j < so1; j++) {
        const int eid = csrS_eid[j];
        float* p = pairs + (size_t)eid * 1026 + col0 + lane * 4;
        __builtin_nontemporal_store(rlo, (f32x2*)p);
        __builtin_nontemporal_store(rhi, (f32x2*)(p + 2));
    }
    // pair rows, dst half: +513 cols -> 4-mod-8 byte alignment -> scalar dwords
    for (int j = d0; j < d1; j++) {
        const int eid = csrD_eid[j];
        float* p = pairs + (size_t)eid * 1026 + 513 + col0 + lane * 4;
        __builtin_nontemporal_store(r.x, p);
        __builtin_nontemporal_store(r.y, p + 1);
        __builtin_nontemporal_store(r.z, p + 2);
        __builtin_nontemporal_store(r.w, p + 3);
    }

    if (hhi) {  // split for next layer's MFMA GEMM
        const unsigned short h0 = f2bf(r.x), h1 = f2bf(r.y), h2 = f2bf(r.z), h3 = f2bf(r.w);
        const unsigned short l0 = f2bf(r.x - bf2f(h0)), l1 = f2bf(r.y - bf2f(h1)),
                             l2 = f2bf(r.z - bf2f(h2)), l3 = f2bf(r.w - bf2f(h3));
        *(ushort4*)(hhi + (size_t)v * 256 + lane * 4) = make_ushort4(h0, h1, h2, h3);
        *(ushort4*)(hlo + (size_t)v * 256 + lane * 4) = make_ushort4(l0, l1, l2, l3);
    }
    if (W2) {  // fused layer-3 row-dot: sv[v] = dot(h2[v,:], W2)
        const float4 w4 = *(const float4*)(W2 + lane * 4);
        float p = r.x * w4.x + r.y * w4.y + r.z * w4.z + r.w * w4.w;
        for (int ofs = 32; ofs > 0; ofs >>= 1) p += __shfl_down(p, ofs, 64);
        if (lane == 0) sv[v] = p;
    }

    // partial logits: pl[v][c] (+)= sum_j h[col0+j] * Wc[col0+j][c]
    const float* __restrict__ wcp = Wc + (size_t)(col0 + lane * 4) * 10;
    float pc[10];
#pragma unroll
    for (int c = 0; c < 10; c++)
        pc[c] = r.x * wcp[c] + r.y * wcp[10 + c] + r.z * wcp[20 + c] + r.w * wcp[30 + c];
#pragma unroll
    for (int c = 0; c < 10; c++) {
        float q = pc[c];
        for (int ofs = 32; ofs > 0; ofs >>= 1) q += __shfl_down(q, ofs, 64);
        if (lane == 0) {
            float* dp = pl + (size_t)v * 10 + c;
            *dp = accum ? (*dp + q) : q;
        }
    }
}

// ---------------- layer-3 scalar aggregate + logits finalize + h3 pair scatter ----------------
__global__ void k_agg_scalar(const float* __restrict__ sv, const float* __restrict__ b2,
                             const int* __restrict__ deg_d,
                             const int* __restrict__ offD, const int* __restrict__ csrD_src,
                             const float* __restrict__ csrD_w, const int* __restrict__ csrD_eid,
                             const int* __restrict__ offS, const int* __restrict__ csrS_eid,
                             const float* __restrict__ Wc, const float* __restrict__ bc,
                             const float* __restrict__ pl,
                             float* __restrict__ nf, float* __restrict__ pairs,
                             float* __restrict__ logits, int n) {
    const int v = blockIdx.x * blockDim.x + threadIdx.x;
    if (v >= n) return;
    const float dii = 1.0f / (float)(deg_d[v] + 1);
    float acc = dii * sv[v];
    const int d0 = offD[v], d1 = offD[v + 1];
    for (int idx = d0; idx < d1; idx++) acc += csrD_w[idx] * sv[csrD_src[idx]];
    const float h3 = tanhf(acc + b2[0]);
    nf[(size_t)v * 513 + 512] = h3;
#pragma unroll
    for (int c = 0; c < 10; c++)
        logits[(size_t)v * 10 + c] = pl[(size_t)v * 10 + c] + h3 * Wc[5120 + c] + bc[c];
    const int so1 = offS[v + 1];
    for (int j = offS[v]; j < so1; j++)
        __builtin_nontemporal_store(h3, pairs + (size_t)csrS_eid[j] * 1026 + 512);
    for (int j = d0; j < d1; j++)
        __builtin_nontemporal_store(h3, pairs + (size_t)csrD_eid[j] * 1026 + 1025);
}

extern "C" void kernel_launch(void* const* d_in, const int* in_sizes, int n_in,
                              void* d_out, int out_size, void* d_ws, size_t ws_size,
                              hipStream_t stream) {
    const float* x  = (const float*)d_in[0];
    const int*   ei = (const int*)d_in[1];
    const float* W0 = (const float*)d_in[2];
    const float* b0 = (const float*)d_in[3];
    const float* W1 = (const float*)d_in[4];
    const float* b1 = (const float*)d_in[5];
    const float* W2 = (const float*)d_in[6];
    const float* b2 = (const float*)d_in[7];
    const float* Wc = (const float*)d_in[8];
    const float* bc = (const float*)d_in[9];

    const int n = in_sizes[0] / 768;   // 20000
    const int e = in_sizes[1] / 2;     // 160000
    const int* src  = ei;
    const int* dstp = ei + e;

    float* out    = (float*)d_out;
    float* logits = out;
    float* nf     = out + (size_t)n * 10;
    float* pairs  = nf + (size_t)n * 513;

    char* w = (char*)d_ws;
    auto alloc = [&](size_t bytes) { char* p = w; w += (bytes + 255) & ~(size_t)255; return p; };
    int*   deg2     = (int*)alloc((size_t)2 * n * 4);  // [deg_d | deg_s], one memset
    int*   deg_d    = deg2;
    int*   deg_s    = deg2 + n;
    int*   off_d    = (int*)alloc((size_t)(n + 1) * 4);
    int*   off_s    = (int*)alloc((size_t)(n + 1) * 4);
    int*   rank_d   = (int*)alloc((size_t)e * 4);
    int*   rank_s   = (int*)alloc((size_t)e * 4);
    int*   csrD_src = (int*)alloc((size_t)e * 4);
    float* csrD_w   = (float*)alloc((size_t)e * 4);
    int*   csrD_eid = (int*)alloc((size_t)e * 4);
    int*   csrS_eid = (int*)alloc((size_t)e * 4);
    unsigned short* xhi   = (unsigned short*)alloc((size_t)n * 768 * 2);
    unsigned short* xlo   = (unsigned short*)alloc((size_t)n * 768 * 2);
    unsigned short* w0thi = (unsigned short*)alloc((size_t)256 * 768 * 2);
    unsigned short* w0tlo = (unsigned short*)alloc((size_t)256 * 768 * 2);
    unsigned short* w1thi = (unsigned short*)alloc((size_t)256 * 256 * 2);
    unsigned short* w1tlo = (unsigned short*)alloc((size_t)256 * 256 * 2);
    float* t   = (float*)alloc((size_t)n * 256 * 4);
    unsigned short* hhi = (unsigned short*)alloc((size_t)n * 256 * 2);
    unsigned short* hlo = (unsigned short*)alloc((size_t)n * 256 * 2);
    float* sv  = (float*)alloc((size_t)n * 4);
    float* pl  = (float*)alloc((size_t)n * 10 * 4);

    hipMemsetAsync(deg2, 0, (size_t)2 * n * 4, stream);

    // CSR build, both directions (rank recorded in hist pass)
    k_hist2<<<(e + 255) / 256, 256, 0, stream>>>(src, dstp, deg_d, deg_s, rank_d, rank_s, e);
    k_scan2<<<1, 1024, 0, stream>>>(deg_d, off_d, deg_s, off_s, n, e);
    k_scatter2<<<(e + 255) / 256, 256, 0, stream>>>(src, dstp, deg_d, off_d, off_s,
                                                    rank_d, rank_s, csrD_src, csrD_w,
                                                    csrD_eid, csrS_eid, e);

    // bf16 hi/lo splits for MFMA
    k_split_x<<<2048, 256, 0, stream>>>(x, xhi, xlo, n * 768 / 4);
    k_split_wt<<<(768 * 256 + 255) / 256, 256, 0, stream>>>(W0, w0thi, w0tlo, 768, 256);
    k_split_wt<<<(256 * 256 + 255) / 256, 256, 0, stream>>>(W1, w1thi, w1tlo, 256, 256);

    const int mb = (n + 127) / 128;

    // layer 1: t = x @ W0 (split-bf16 MFMA); h1 = tanh(agg(t)+b0); scatter nf/pairs; pl =
    k_gemm_mfma<<<dim3(2, mb), 256, 0, stream>>>(xhi, xlo, w0thi, w0tlo, t, n, 768);
    k_aggregate<<<(n + 3) / 4, 256, 0, stream>>>(t, b0, deg_d, off_d, csrD_src, csrD_w, csrD_eid,
                                                 off_s, csrS_eid, nf, pairs, 0,
                                                 hhi, hlo, nullptr, nullptr, Wc, pl, 0, n);

    // layer 2: t = h1 @ W1; h2 = tanh(agg(t)+b1); scatter; pl +=; fused sv = h2 @ W2
    k_gemm_mfma<<<dim3(2, mb), 256, 0, stream>>>(hhi, hlo, w1thi, w1tlo, t, n, 256);
    k_aggregate<<<(n + 3) / 4, 256, 0, stream>>>(t, b1, deg_d, off_d, csrD_src, csrD_w, csrD_eid,
                                                 off_s, csrS_eid, nf, pairs, 256,
                                                 nullptr, nullptr, W2, sv, Wc, pl, 1, n);

    // layer 3 + logits finalize + h3 pair scatter
    k_agg_scalar<<<(n + 255) / 256, 256, 0, stream>>>(sv, b2, deg_d, off_d, csrD_src, csrD_w,
                                                      csrD_eid, off_s, csrS_eid, Wc, bc, pl,
                                                      nf, pairs, logits, n);
}

// Round 3
// 1006.894 us; speedup vs baseline: 1.0193x; 1.0193x over previous
//
#include <hip/hip_runtime.h>
#include <math.h>

// Problem constants: N=20000, E=160000, D=768, H=256, C=10
// Outputs (fp32, concatenated): logits [N,10], node_features [N,513], edge_pairs [E,1026]
//
// Structure: edge_pairs scattered at production time from the aggregates (no nf gather);
// classifier fused into aggregates as partial-logit sums; GEMMs are split-bf16 MFMA
// (hi*hi + hi*lo + lo*hi) with 64x64 tiles for occupancy; x's fp32->bf16 split is fused
// into GEMM-1's A-staging (no separate split kernel, no xhi/xlo round-trip).

typedef __attribute__((ext_vector_type(8))) short short8;
typedef __attribute__((ext_vector_type(4))) float f32x4;
typedef __attribute__((ext_vector_type(2))) float f32x2;

static __device__ __forceinline__ unsigned short f2bf(float f) {
    unsigned u = __float_as_uint(f);
    u += 0x7fffu + ((u >> 16) & 1u);  // RNE
    return (unsigned short)(u >> 16);
}
static __device__ __forceinline__ float bf2f(unsigned short h) {
    return __uint_as_float((unsigned)h << 16);
}

// ---------------- CSR build (both directions) ----------------

__global__ void k_hist2(const int* __restrict__ src, const int* __restrict__ dst,
                        int* __restrict__ deg_d, int* __restrict__ deg_s,
                        int* __restrict__ rank_d, int* __restrict__ rank_s, int e) {
    int i = blockIdx.x * blockDim.x + threadIdx.x;
    if (i < e) {
        rank_d[i] = atomicAdd(&deg_d[dst[i]], 1);
        rank_s[i] = atomicAdd(&deg_s[src[i]], 1);
    }
}

// single-block, thread-coarsened exclusive scan of two arrays.
__global__ __launch_bounds__(1024) void k_scan2(const int* __restrict__ degA, int* __restrict__ offA,
                                                const int* __restrict__ degB, int* __restrict__ offB,
                                                int n, int total) {
    __shared__ int part[1024];
    const int t = threadIdx.x;
    const int per = (n + 1023) >> 10;
    const int s0 = t * per;
    int s1 = s0 + per; if (s1 > n) s1 = n;
    for (int pass = 0; pass < 2; pass++) {
        const int* __restrict__ deg = pass ? degB : degA;
        int* __restrict__ off = pass ? offB : offA;
        int s = 0;
        for (int i = s0; i < s1; i++) s += deg[i];
        part[t] = s;
        __syncthreads();
        int x = s;
        for (int ofs = 1; ofs < 1024; ofs <<= 1) {
            int add = (t >= ofs) ? part[t - ofs] : 0;
            __syncthreads();
            x += add;
            part[t] = x;
            __syncthreads();
        }
        int run = x - s;  // exclusive prefix of this chunk
        for (int i = s0; i < s1; i++) { off[i] = run; run += deg[i]; }
        if (t == 0) off[n] = total;
        __syncthreads();
    }
}

__global__ void k_scatter2(const int* __restrict__ src, const int* __restrict__ dst,
                           const int* __restrict__ deg_d,
                           const int* __restrict__ off_d, const int* __restrict__ off_s,
                           const int* __restrict__ rank_d, const int* __restrict__ rank_s,
                           int* __restrict__ csrD_src, float* __restrict__ csrD_w,
                           int* __restrict__ csrD_eid, int* __restrict__ csrS_eid, int e) {
    int i = blockIdx.x * blockDim.x + threadIdx.x;
    if (i < e) {
        const int d = dst[i], s = src[i];
        const int posd = off_d[d] + rank_d[i];
        csrD_src[posd] = s;
        // norm = dinv[s]*dinv[d], dinv from IN-degree (+1 self-loop), matching reference
        csrD_w[posd] = rsqrtf((float)(deg_d[s] + 1) * (float)(deg_d[d] + 1));
        csrD_eid[posd] = i;
        csrS_eid[off_s[s] + rank_s[i]] = i;
    }
}

// W [K,N] fp32 -> Wt [N,K] bf16 hi/lo (transposed so MFMA B-frags are contiguous-K)
__global__ void k_split_wt(const float* __restrict__ W, unsigned short* __restrict__ wthi,
                           unsigned short* __restrict__ wtlo, int K, int N) {
    int idx = blockIdx.x * blockDim.x + threadIdx.x;
    if (idx >= K * N) return;
    const int k = idx / N, nn = idx - k * N;
    const float v = W[idx];
    const unsigned short h = f2bf(v);
    wthi[(size_t)nn * K + k] = h;
    wtlo[(size_t)nn * K + k] = f2bf(v - bf2f(h));
}

// ---------------- split-bf16 MFMA GEMM: C[M,256] = A[M,K] @ (Bhi+Blo)^T[K,256] ----------------
// BM=BN=64, BK=32, 256 threads (2x2 waves, each 32x32 via 2x2 16x16x32 fragments).
// AFP32: A is fp32 (rows 16B-aligned); hi/lo split done in-register during staging.
// else:  A is pre-split bf16 hi/lo.
// 3-term split: hi*hi + hi*lo + lo*hi. 16B-granule XOR swizzle -> conflict-free b128 reads.
template <bool AFP32>
__global__ __launch_bounds__(256) void k_gemm64(
    const float* __restrict__ Af, int lda,
    const unsigned short* __restrict__ Ahi, const unsigned short* __restrict__ Alo,
    const unsigned short* __restrict__ Bhi, const unsigned short* __restrict__ Blo,
    float* __restrict__ C, int M, int K)
{
    __shared__ short As_hi[64 * 32], As_lo[64 * 32], Bs_hi[64 * 32], Bs_lo[64 * 32];
    const int tid = threadIdx.x;
    const int m0 = blockIdx.y * 64, n0 = blockIdx.x * 64;
    const int lane = tid & 63;
    const int wave = tid >> 6;
    const int wr = wave >> 1, wc = wave & 1;
    const int l15 = lane & 15, l16 = lane >> 4;

    f32x4 acc[2][2] = {};

    // staging: thread -> (row = tid>>2, granule g = tid&3 of 8 shorts)
    const int srow = tid >> 2;
    const int g = tid & 3;
    const int sofs = srow * 32 + ((g ^ ((srow >> 1) & 3)) << 3);
    const bool aok = (m0 + srow) < M;

    for (int k0 = 0; k0 < K; k0 += 32) {
        short8 ah = {0,0,0,0,0,0,0,0}, al = {0,0,0,0,0,0,0,0};
        if (AFP32) {
            if (aok) {
                const float* ap = Af + (size_t)(m0 + srow) * lda + k0 + g * 8;
                const float4 v0 = *(const float4*)ap;
                const float4 v1 = *(const float4*)(ap + 4);
                const float vv[8] = {v0.x, v0.y, v0.z, v0.w, v1.x, v1.y, v1.z, v1.w};
#pragma unroll
                for (int j = 0; j < 8; j++) {
                    const unsigned short h = f2bf(vv[j]);
                    ah[j] = (short)h;
                    al[j] = (short)f2bf(vv[j] - bf2f(h));
                }
            }
        } else {
            if (aok) {
                ah = *(const short8*)(Ahi + (size_t)(m0 + srow) * K + k0 + g * 8);
                al = *(const short8*)(Alo + (size_t)(m0 + srow) * K + k0 + g * 8);
            }
        }
        const short8 bh = *(const short8*)(Bhi + (size_t)(n0 + srow) * K + k0 + g * 8);
        const short8 bl = *(const short8*)(Blo + (size_t)(n0 + srow) * K + k0 + g * 8);

        __syncthreads();  // protect previous iteration's reads
        *(short8*)&As_hi[sofs] = ah;
        *(short8*)&As_lo[sofs] = al;
        *(short8*)&Bs_hi[sofs] = bh;
        *(short8*)&Bs_lo[sofs] = bl;
        __syncthreads();

        short8 afh[2], afl[2];
#pragma unroll
        for (int i = 0; i < 2; i++) {
            const int r = wr * 32 + i * 16 + l15;
            const int off = r * 32 + ((l16 ^ ((r >> 1) & 3)) << 3);
            afh[i] = *(const short8*)&As_hi[off];
            afl[i] = *(const short8*)&As_lo[off];
        }
#pragma unroll
        for (int j = 0; j < 2; j++) {
            const int r = wc * 32 + j * 16 + l15;
            const int off = r * 32 + ((l16 ^ ((r >> 1) & 3)) << 3);
            const short8 bfh = *(const short8*)&Bs_hi[off];
            const short8 bfl = *(const short8*)&Bs_lo[off];
#pragma unroll
            for (int i = 0; i < 2; i++) {
                acc[i][j] = __builtin_amdgcn_mfma_f32_16x16x32_bf16(afh[i], bfh, acc[i][j], 0, 0, 0);
                acc[i][j] = __builtin_amdgcn_mfma_f32_16x16x32_bf16(afh[i], bfl, acc[i][j], 0, 0, 0);
                acc[i][j] = __builtin_amdgcn_mfma_f32_16x16x32_bf16(afl[i], bfh, acc[i][j], 0, 0, 0);
            }
        }
    }

    // C/D layout (verified m89/m91): col = lane&15, row = (lane>>4)*4 + q
#pragma unroll
    for (int i = 0; i < 2; i++) {
#pragma unroll
        for (int q = 0; q < 4; q++) {
            const int m = m0 + wr * 32 + i * 16 + l16 * 4 + q;
            if (m < M) {
#pragma unroll
                for (int j = 0; j < 2; j++)
                    C[(size_t)m * 256 + n0 + wc * 32 + j * 16 + l15] = acc[i][j][q];
            }
        }
    }
}

// ---------------- aggregation (dim=256): wave per node ----------------
// h[v] = tanh(sum_nbr w*t[u] + (1/(deg+1))*t[v] + b)
// Writes: nf slab, pair-row slabs (src half via csrS, dst half via csrD), partial logits;
// optional bf16 hi/lo split out (layer1), optional fused W2 row-dot -> sv (layer2).
__global__ __launch_bounds__(256) void k_aggregate(
    const float* __restrict__ t, const float* __restrict__ bias,
    const int* __restrict__ deg_d,
    const int* __restrict__ offD, const int* __restrict__ csrD_src,
    const float* __restrict__ csrD_w, const int* __restrict__ csrD_eid,
    const int* __restrict__ offS, const int* __restrict__ csrS_eid,
    float* __restrict__ nf, float* __restrict__ pairs, int col0,
    unsigned short* __restrict__ hhi, unsigned short* __restrict__ hlo,
    const float* __restrict__ W2, float* __restrict__ sv,
    const float* __restrict__ Wc, float* __restrict__ pl, int accum, int n)
{
    const int v = blockIdx.x * 4 + (threadIdx.x >> 6);
    if (v >= n) return;
    const int lane = threadIdx.x & 63;
    const float dii = 1.0f / (float)(deg_d[v] + 1);
    const float4 tb = *(const float4*)(bias + lane * 4);
    const float4 a  = *(const float4*)(t + (size_t)v * 256 + lane * 4);
    float4 s4 = make_float4(dii * a.x, dii * a.y, dii * a.z, dii * a.w);
    const int d0 = offD[v], d1 = offD[v + 1];
    for (int idx = d0; idx < d1; idx++) {
        const int u = csrD_src[idx];
        const float w = csrD_w[idx];
        const float4 tv = *(const float4*)(t + (size_t)u * 256 + lane * 4);
        s4.x = fmaf(w, tv.x, s4.x);
        s4.y = fmaf(w, tv.y, s4.y);
        s4.z = fmaf(w, tv.z, s4.z);
        s4.w = fmaf(w, tv.w, s4.w);
    }
    float4 r;
    r.x = tanhf(s4.x + tb.x);
    r.y = tanhf(s4.y + tb.y);
    r.z = tanhf(s4.z + tb.z);
    r.w = tanhf(s4.w + tb.w);

    // nf slab (scalar dwords; rows only 4B-aligned)
    float* nfp = nf + (size_t)v * 513 + col0 + lane * 4;
    nfp[0] = r.x; nfp[1] = r.y; nfp[2] = r.z; nfp[3] = r.w;

    // pair rows, src half: byte base = eid*4104 + col0*4 + lane*16 -> 8B aligned
    const f32x2 rlo = {r.x, r.y}, rhi = {r.z, r.w};
    const int so0 = offS[v], so1 = offS[v + 1];
    for (int j = so0; j < so1; j++) {
        const int eid = csrS_eid[j];
        float* p = pairs + (size_t)eid * 1026 + col0 + lane * 4;
        __builtin_nontemporal_store(rlo, (f32x2*)p);
        __builtin_nontemporal_store(rhi, (f32x2*)(p + 2));
    }
    // pair rows, dst half: +513 cols -> 4-mod-8 byte alignment -> scalar dwords
    for (int j = d0; j < d1; j++) {
        const int eid = csrD_eid[j];
        float* p = pairs + (size_t)eid * 1026 + 513 + col0 + lane * 4;
        __builtin_nontemporal_store(r.x, p);
        __builtin_nontemporal_store(r.y, p + 1);
        __builtin_nontemporal_store(r.z, p + 2);
        __builtin_nontemporal_store(r.w, p + 3);
    }

    if (hhi) {  // split for next layer's MFMA GEMM
        const unsigned short h0 = f2bf(r.x), h1 = f2bf(r.y), h2 = f2bf(r.z), h3 = f2bf(r.w);
        const unsigned short l0 = f2bf(r.x - bf2f(h0)), l1 = f2bf(r.y - bf2f(h1)),
                             l2 = f2bf(r.z - bf2f(h2)), l3 = f2bf(r.w - bf2f(h3));
        *(ushort4*)(hhi + (size_t)v * 256 + lane * 4) = make_ushort4(h0, h1, h2, h3);
        *(ushort4*)(hlo + (size_t)v * 256 + lane * 4) = make_ushort4(l0, l1, l2, l3);
    }
    if (W2) {  // fused layer-3 row-dot: sv[v] = dot(h2[v,:], W2)
        const float4 w4 = *(const float4*)(W2 + lane * 4);
        float p = r.x * w4.x + r.y * w4.y + r.z * w4.z + r.w * w4.w;
        for (int ofs = 32; ofs > 0; ofs >>= 1) p += __shfl_down(p, ofs, 64);
        if (lane == 0) sv[v] = p;
    }

    // partial logits: pl[v][c] (+)= sum_j h[col0+j] * Wc[col0+j][c]
    const float* __restrict__ wcp = Wc + (size_t)(col0 + lane * 4) * 10;
    float pc[10];
#pragma unroll
    for (int c = 0; c < 10; c++)
        pc[c] = r.x * wcp[c] + r.y * wcp[10 + c] + r.z * wcp[20 + c] + r.w * wcp[30 + c];
#pragma unroll
    for (int c = 0; c < 10; c++) {
        float q = pc[c];
        for (int ofs = 32; ofs > 0; ofs >>= 1) q += __shfl_down(q, ofs, 64);
        if (lane == 0) {
            float* dp = pl + (size_t)v * 10 + c;
            *dp = accum ? (*dp + q) : q;
        }
    }
}

// ---------------- layer-3 scalar aggregate + logits finalize + h3 pair scatter ----------------
__global__ void k_agg_scalar(const float* __restrict__ sv, const float* __restrict__ b2,
                             const int* __restrict__ deg_d,
                             const int* __restrict__ offD, const int* __restrict__ csrD_src,
                             const float* __restrict__ csrD_w, const int* __restrict__ csrD_eid,
                             const int* __restrict__ offS, const int* __restrict__ csrS_eid,
                             const float* __restrict__ Wc, const float* __restrict__ bc,
                             const float* __restrict__ pl,
                             float* __restrict__ nf, float* __restrict__ pairs,
                             float* __restrict__ logits, int n) {
    const int v = blockIdx.x * blockDim.x + threadIdx.x;
    if (v >= n) return;
    const float dii = 1.0f / (float)(deg_d[v] + 1);
    float acc = dii * sv[v];
    const int d0 = offD[v], d1 = offD[v + 1];
    for (int idx = d0; idx < d1; idx++) acc += csrD_w[idx] * sv[csrD_src[idx]];
    const float h3 = tanhf(acc + b2[0]);
    nf[(size_t)v * 513 + 512] = h3;
#pragma unroll
    for (int c = 0; c < 10; c++)
        logits[(size_t)v * 10 + c] = pl[(size_t)v * 10 + c] + h3 * Wc[5120 + c] + bc[c];
    const int so1 = offS[v + 1];
    for (int j = offS[v]; j < so1; j++)
        __builtin_nontemporal_store(h3, pairs + (size_t)csrS_eid[j] * 1026 + 512);
    for (int j = d0; j < d1; j++)
        __builtin_nontemporal_store(h3, pairs + (size_t)csrD_eid[j] * 1026 + 1025);
}

extern "C" void kernel_launch(void* const* d_in, const int* in_sizes, int n_in,
                              void* d_out, int out_size, void* d_ws, size_t ws_size,
                              hipStream_t stream) {
    const float* x  = (const float*)d_in[0];
    const int*   ei = (const int*)d_in[1];
    const float* W0 = (const float*)d_in[2];
    const float* b0 = (const float*)d_in[3];
    const float* W1 = (const float*)d_in[4];
    const float* b1 = (const float*)d_in[5];
    const float* W2 = (const float*)d_in[6];
    const float* b2 = (const float*)d_in[7];
    const float* Wc = (const float*)d_in[8];
    const float* bc = (const float*)d_in[9];

    const int n = in_sizes[0] / 768;   // 20000
    const int e = in_sizes[1] / 2;     // 160000
    const int* src  = ei;
    const int* dstp = ei + e;

    float* out    = (float*)d_out;
    float* logits = out;
    float* nf     = out + (size_t)n * 10;
    float* pairs  = nf + (size_t)n * 513;

    char* w = (char*)d_ws;
    auto alloc = [&](size_t bytes) { char* p = w; w += (bytes + 255) & ~(size_t)255; return p; };
    int*   deg2     = (int*)alloc((size_t)2 * n * 4);  // [deg_d | deg_s], one memset
    int*   deg_d    = deg2;
    int*   deg_s    = deg2 + n;
    int*   off_d    = (int*)alloc((size_t)(n + 1) * 4);
    int*   off_s    = (int*)alloc((size_t)(n + 1) * 4);
    int*   rank_d   = (int*)alloc((size_t)e * 4);
    int*   rank_s   = (int*)alloc((size_t)e * 4);
    int*   csrD_src = (int*)alloc((size_t)e * 4);
    float* csrD_w   = (float*)alloc((size_t)e * 4);
    int*   csrD_eid = (int*)alloc((size_t)e * 4);
    int*   csrS_eid = (int*)alloc((size_t)e * 4);
    unsigned short* w0thi = (unsigned short*)alloc((size_t)256 * 768 * 2);
    unsigned short* w0tlo = (unsigned short*)alloc((size_t)256 * 768 * 2);
    unsigned short* w1thi = (unsigned short*)alloc((size_t)256 * 256 * 2);
    unsigned short* w1tlo = (unsigned short*)alloc((size_t)256 * 256 * 2);
    float* t   = (float*)alloc((size_t)n * 256 * 4);
    unsigned short* hhi = (unsigned short*)alloc((size_t)n * 256 * 2);
    unsigned short* hlo = (unsigned short*)alloc((size_t)n * 256 * 2);
    float* sv  = (float*)alloc((size_t)n * 4);
    float* pl  = (float*)alloc((size_t)n * 10 * 4);

    hipMemsetAsync(deg2, 0, (size_t)2 * n * 4, stream);

    // CSR build, both directions (rank recorded in hist pass)
    k_hist2<<<(e + 255) / 256, 256, 0, stream>>>(src, dstp, deg_d, deg_s, rank_d, rank_s, e);
    k_scan2<<<1, 1024, 0, stream>>>(deg_d, off_d, deg_s, off_s, n, e);
    k_scatter2<<<(e + 255) / 256, 256, 0, stream>>>(src, dstp, deg_d, off_d, off_s,
                                                    rank_d, rank_s, csrD_src, csrD_w,
                                                    csrD_eid, csrS_eid, e);

    // bf16 hi/lo splits for weights (x split is fused into GEMM-1 staging)
    k_split_wt<<<(768 * 256 + 255) / 256, 256, 0, stream>>>(W0, w0thi, w0tlo, 768, 256);
    k_split_wt<<<(256 * 256 + 255) / 256, 256, 0, stream>>>(W1, w1thi, w1tlo, 256, 256);

    const int mb = (n + 63) / 64;

    // layer 1: t = x @ W0 (fused-split MFMA); h1 = tanh(agg(t)+b0); scatter nf/pairs; pl =
    k_gemm64<true><<<dim3(4, mb), 256, 0, stream>>>(x, 768, nullptr, nullptr,
                                                    w0thi, w0tlo, t, n, 768);
    k_aggregate<<<(n + 3) / 4, 256, 0, stream>>>(t, b0, deg_d, off_d, csrD_src, csrD_w, csrD_eid,
                                                 off_s, csrS_eid, nf, pairs, 0,
                                                 hhi, hlo, nullptr, nullptr, Wc, pl, 0, n);

    // layer 2: t = h1 @ W1; h2 = tanh(agg(t)+b1); scatter; pl +=; fused sv = h2 @ W2
    k_gemm64<false><<<dim3(4, mb), 256, 0, stream>>>(nullptr, 0, hhi, hlo,
                                                     w1thi, w1tlo, t, n, 256);
    k_aggregate<<<(n + 3) / 4, 256, 0, stream>>>(t, b1, deg_d, off_d, csrD_src, csrD_w, csrD_eid,
                                                 off_s, csrS_eid, nf, pairs, 256,
                                                 nullptr, nullptr, W2, sv, Wc, pl, 1, n);

    // layer 3 + logits finalize + h3 pair scatter
    k_agg_scalar<<<(n + 255) / 256, 256, 0, stream>>>(sv, b2, deg_d, off_d, csrD_src, csrD_w,
                                                      csrD_eid, off_s, csrS_eid, Wc, bc, pl,
                                                      nf, pairs, logits, n);
}

// Round 4
// 1004.359 us; speedup vs baseline: 1.0219x; 1.0025x over previous
//
#include <hip/hip_runtime.h>
#include <math.h>

// Problem constants: N=20000, E=160000, D=768, H=256, C=10
// Outputs (fp32, concatenated): logits [N,10], node_features [N,513], edge_pairs [E,1026]
//
// Structure: edge_pairs scattered at production time from the aggregates (no nf gather);
// classifier fused into aggregates as partial-logit sums; GEMMs are split-bf16 MFMA
// (hi*hi + hi*lo + lo*hi), 64x64 tiles, XCD-grouped grid for A L2-reuse; x's fp32->bf16
// split fused into GEMM-1 staging; CSR (src,w) packed int2 + pipelined gather loop.

typedef __attribute__((ext_vector_type(8))) short short8;
typedef __attribute__((ext_vector_type(4))) float f32x4;
typedef __attribute__((ext_vector_type(2))) float f32x2;

static __device__ __forceinline__ unsigned short f2bf(float f) {
    unsigned u = __float_as_uint(f);
    u += 0x7fffu + ((u >> 16) & 1u);  // RNE
    return (unsigned short)(u >> 16);
}
static __device__ __forceinline__ float bf2f(unsigned short h) {
    return __uint_as_float((unsigned)h << 16);
}
static __device__ __forceinline__ void nt1(float v, float* p) {
    __builtin_nontemporal_store(v, p);
}
static __device__ __forceinline__ void nt2(f32x2 v, float* p) {
    __builtin_nontemporal_store(v, (f32x2*)p);
}
static __device__ __forceinline__ void nt4(f32x4 v, float* p) {
    __builtin_nontemporal_store(v, (f32x4*)p);
}

// ---------------- CSR build (both directions) ----------------

__global__ void k_hist2(const int* __restrict__ src, const int* __restrict__ dst,
                        int* __restrict__ deg_d, int* __restrict__ deg_s,
                        int* __restrict__ rank_d, int* __restrict__ rank_s, int e) {
    int i = blockIdx.x * blockDim.x + threadIdx.x;
    if (i < e) {
        rank_d[i] = atomicAdd(&deg_d[dst[i]], 1);
        rank_s[i] = atomicAdd(&deg_s[src[i]], 1);
    }
}

// single-block, thread-coarsened exclusive scan of two arrays.
__global__ __launch_bounds__(1024) void k_scan2(const int* __restrict__ degA, int* __restrict__ offA,
                                                const int* __restrict__ degB, int* __restrict__ offB,
                                                int n, int total) {
    __shared__ int part[1024];
    const int t = threadIdx.x;
    const int per = (n + 1023) >> 10;
    const int s0 = t * per;
    int s1 = s0 + per; if (s1 > n) s1 = n;
    for (int pass = 0; pass < 2; pass++) {
        const int* __restrict__ deg = pass ? degB : degA;
        int* __restrict__ off = pass ? offB : offA;
        int s = 0;
        for (int i = s0; i < s1; i++) s += deg[i];
        part[t] = s;
        __syncthreads();
        int x = s;
        for (int ofs = 1; ofs < 1024; ofs <<= 1) {
            int add = (t >= ofs) ? part[t - ofs] : 0;
            __syncthreads();
            x += add;
            part[t] = x;
            __syncthreads();
        }
        int run = x - s;  // exclusive prefix of this chunk
        for (int i = s0; i < s1; i++) { off[i] = run; run += deg[i]; }
        if (t == 0) off[n] = total;
        __syncthreads();
    }
}

__global__ void k_scatter2(const int* __restrict__ src, const int* __restrict__ dst,
                           const int* __restrict__ deg_d,
                           const int* __restrict__ off_d, const int* __restrict__ off_s,
                           const int* __restrict__ rank_d, const int* __restrict__ rank_s,
                           int2* __restrict__ csrD_sw,
                           int* __restrict__ csrD_eid, int* __restrict__ csrS_eid, int e) {
    int i = blockIdx.x * blockDim.x + threadIdx.x;
    if (i < e) {
        const int d = dst[i], s = src[i];
        const int posd = off_d[d] + rank_d[i];
        // norm = dinv[s]*dinv[d], dinv from IN-degree (+1 self-loop), matching reference
        const float w = rsqrtf((float)(deg_d[s] + 1) * (float)(deg_d[d] + 1));
        csrD_sw[posd] = make_int2(s, __float_as_int(w));
        csrD_eid[posd] = i;
        csrS_eid[off_s[s] + rank_s[i]] = i;
    }
}

// W0 [768,256] and W1 [256,256] fp32 -> transposed bf16 hi/lo in one launch
__global__ void k_split_wt2(const float* __restrict__ W0, unsigned short* __restrict__ w0thi,
                            unsigned short* __restrict__ w0tlo,
                            const float* __restrict__ W1, unsigned short* __restrict__ w1thi,
                            unsigned short* __restrict__ w1tlo) {
    int idx = blockIdx.x * blockDim.x + threadIdx.x;
    const float* W; unsigned short *th, *tl; int K;
    if (idx < 768 * 256) { W = W0; th = w0thi; tl = w0tlo; K = 768; }
    else { idx -= 768 * 256; if (idx >= 256 * 256) return; W = W1; th = w1thi; tl = w1tlo; K = 256; }
    const int k = idx >> 8, nn = idx & 255;  // N=256 for both
    const float v = W[idx];
    const unsigned short h = f2bf(v);
    th[(size_t)nn * K + k] = h;
    tl[(size_t)nn * K + k] = f2bf(v - bf2f(h));
}

// ---------------- split-bf16 MFMA GEMM: C[M,256] = A[M,K] @ (Bhi+Blo)^T[K,256] ----------------
// BM=BN=64, BK=32, 256 threads (4 waves, each 32x32 via 2x2 16x16x32 fragments).
// 1D XCD-grouped grid: xcd = bid&7 (round-robin dispatch), strips chunked per XCD,
// col-block fastest within XCD -> the 4 col-blocks of a strip share that XCD's L2 for A.
template <bool AFP32>
__global__ __launch_bounds__(256) void k_gemm64(
    const float* __restrict__ Af, int lda,
    const unsigned short* __restrict__ Ahi, const unsigned short* __restrict__ Alo,
    const unsigned short* __restrict__ Bhi, const unsigned short* __restrict__ Blo,
    float* __restrict__ C, int M, int K, int per)
{
    __shared__ short As_hi[64 * 32], As_lo[64 * 32], Bs_hi[64 * 32], Bs_lo[64 * 32];
    const int xcd = blockIdx.x & 7, slot = blockIdx.x >> 3;
    const int strip = xcd * per + (slot >> 2);
    if (strip >= (M + 63) / 64) return;
    const int m0 = strip * 64, n0 = (slot & 3) * 64;

    const int tid = threadIdx.x;
    const int lane = tid & 63;
    const int wave = tid >> 6;
    const int wr = wave >> 1, wc = wave & 1;
    const int l15 = lane & 15, l16 = lane >> 4;

    f32x4 acc[2][2] = {};

    // staging: thread -> (row = tid>>2, granule g = tid&3 of 8 shorts)
    const int srow = tid >> 2;
    const int g = tid & 3;
    const int sofs = srow * 32 + ((g ^ ((srow >> 1) & 3)) << 3);
    const bool aok = (m0 + srow) < M;

    for (int k0 = 0; k0 < K; k0 += 32) {
        short8 ah = {0,0,0,0,0,0,0,0}, al = {0,0,0,0,0,0,0,0};
        if (AFP32) {
            if (aok) {
                const float* ap = Af + (size_t)(m0 + srow) * lda + k0 + g * 8;
                const float4 v0 = *(const float4*)ap;
                const float4 v1 = *(const float4*)(ap + 4);
                const float vv[8] = {v0.x, v0.y, v0.z, v0.w, v1.x, v1.y, v1.z, v1.w};
#pragma unroll
                for (int j = 0; j < 8; j++) {
                    const unsigned short h = f2bf(vv[j]);
                    ah[j] = (short)h;
                    al[j] = (short)f2bf(vv[j] - bf2f(h));
                }
            }
        } else {
            if (aok) {
                ah = *(const short8*)(Ahi + (size_t)(m0 + srow) * K + k0 + g * 8);
                al = *(const short8*)(Alo + (size_t)(m0 + srow) * K + k0 + g * 8);
            }
        }
        const short8 bh = *(const short8*)(Bhi + (size_t)(n0 + srow) * K + k0 + g * 8);
        const short8 bl = *(const short8*)(Blo + (size_t)(n0 + srow) * K + k0 + g * 8);

        __syncthreads();  // protect previous iteration's reads
        *(short8*)&As_hi[sofs] = ah;
        *(short8*)&As_lo[sofs] = al;
        *(short8*)&Bs_hi[sofs] = bh;
        *(short8*)&Bs_lo[sofs] = bl;
        __syncthreads();

        short8 afh[2], afl[2];
#pragma unroll
        for (int i = 0; i < 2; i++) {
            const int r = wr * 32 + i * 16 + l15;
            const int off = r * 32 + ((l16 ^ ((r >> 1) & 3)) << 3);
            afh[i] = *(const short8*)&As_hi[off];
            afl[i] = *(const short8*)&As_lo[off];
        }
#pragma unroll
        for (int j = 0; j < 2; j++) {
            const int r = wc * 32 + j * 16 + l15;
            const int off = r * 32 + ((l16 ^ ((r >> 1) & 3)) << 3);
            const short8 bfh = *(const short8*)&Bs_hi[off];
            const short8 bfl = *(const short8*)&Bs_lo[off];
#pragma unroll
            for (int i = 0; i < 2; i++) {
                acc[i][j] = __builtin_amdgcn_mfma_f32_16x16x32_bf16(afh[i], bfh, acc[i][j], 0, 0, 0);
                acc[i][j] = __builtin_amdgcn_mfma_f32_16x16x32_bf16(afh[i], bfl, acc[i][j], 0, 0, 0);
                acc[i][j] = __builtin_amdgcn_mfma_f32_16x16x32_bf16(afl[i], bfh, acc[i][j], 0, 0, 0);
            }
        }
    }

    // C/D layout (verified m89/m91): col = lane&15, row = (lane>>4)*4 + q
#pragma unroll
    for (int i = 0; i < 2; i++) {
#pragma unroll
        for (int q = 0; q < 4; q++) {
            const int m = m0 + wr * 32 + i * 16 + l16 * 4 + q;
            if (m < M) {
#pragma unroll
                for (int j = 0; j < 2; j++)
                    C[(size_t)m * 256 + n0 + wc * 32 + j * 16 + l15] = acc[i][j][q];
            }
        }
    }
}

// ---------------- aggregation (dim=256): wave per node ----------------
// h[v] = tanh(sum_nbr w*t[u] + (1/(deg+1))*t[v] + b)
// Writes: nf slab, pair-row slabs (src half via csrS, dst half via csrD), partial logits;
// optional bf16 hi/lo split out (layer1), optional fused W2 row-dot -> sv (layer2).
__global__ __launch_bounds__(256) void k_aggregate(
    const float* __restrict__ t, const float* __restrict__ bias,
    const int* __restrict__ deg_d,
    const int* __restrict__ offD, const int2* __restrict__ csrD_sw,
    const int* __restrict__ csrD_eid,
    const int* __restrict__ offS, const int* __restrict__ csrS_eid,
    float* __restrict__ nf, float* __restrict__ pairs, int col0,
    unsigned short* __restrict__ hhi, unsigned short* __restrict__ hlo,
    const float* __restrict__ W2, float* __restrict__ sv,
    const float* __restrict__ Wc, float* __restrict__ pl, int accum, int n)
{
    const int v = blockIdx.x * 4 + (threadIdx.x >> 6);
    if (v >= n) return;
    const int lane = threadIdx.x & 63;
    const float dii = 1.0f / (float)(deg_d[v] + 1);
    const float4 tb = *(const float4*)(bias + lane * 4);
    const float4 a  = *(const float4*)(t + (size_t)v * 256 + lane * 4);
    float4 s4 = make_float4(dii * a.x, dii * a.y, dii * a.z, dii * a.w);
    const int d0 = offD[v], d1 = offD[v + 1];
    // pipelined gather: prefetch next (src,w) while current row load is in flight
    int2 pk = (d0 < d1) ? csrD_sw[d0] : make_int2(0, 0);
    for (int idx = d0; idx < d1; idx++) {
        const int2 nk = (idx + 1 < d1) ? csrD_sw[idx + 1] : make_int2(0, 0);
        const float w = __int_as_float(pk.y);
        const float4 tv = *(const float4*)(t + (size_t)pk.x * 256 + lane * 4);
        s4.x = fmaf(w, tv.x, s4.x);
        s4.y = fmaf(w, tv.y, s4.y);
        s4.z = fmaf(w, tv.z, s4.z);
        s4.w = fmaf(w, tv.w, s4.w);
        pk = nk;
    }
    float4 r;
    r.x = tanhf(s4.x + tb.x);
    r.y = tanhf(s4.y + tb.y);
    r.z = tanhf(s4.z + tb.z);
    r.w = tanhf(s4.w + tb.w);
    const f32x4 rv = {r.x, r.y, r.z, r.w};
    const f32x2 rlo = {r.x, r.y}, rhi = {r.z, r.w}, rmid = {r.y, r.z};

    // nf slab: float index 513v+col0+4lane; vector form picked by v&3 (wave-uniform)
    {
        float* p = nf + (size_t)v * 513 + col0 + lane * 4;
        const int ph = v & 3;
        if (ph == 0) {
            nt4(rv, p);
        } else if (ph == 2) {
            nt2(rlo, p); nt2(rhi, p + 2);
        } else {
            nt1(r.x, p); nt2(rmid, p + 1); nt1(r.w, p + 3);
        }
    }

    // pair rows, src half: float base 1026*eid+col0 (+4lane); eid even -> 16B aligned
    const int so0 = offS[v], so1 = offS[v + 1];
    for (int j = so0; j < so1; j++) {
        const int eid = csrS_eid[j];
        float* p = pairs + (size_t)eid * 1026 + col0 + lane * 4;
        if (!(eid & 1)) {
            nt4(rv, p);
        } else {
            nt2(rlo, p); nt2(rhi, p + 2);
        }
    }
    // pair rows, dst half: float base 1026*eid+513+col0 (+4lane) -> odd index always
    for (int j = d0; j < d1; j++) {
        const int eid = csrD_eid[j];
        float* p = pairs + (size_t)eid * 1026 + 513 + col0 + lane * 4;
        nt1(r.x, p); nt2(rmid, p + 1); nt1(r.w, p + 3);
    }

    if (hhi) {  // split for next layer's MFMA GEMM
        const unsigned short h0 = f2bf(r.x), h1 = f2bf(r.y), h2 = f2bf(r.z), h3 = f2bf(r.w);
        const unsigned short l0 = f2bf(r.x - bf2f(h0)), l1 = f2bf(r.y - bf2f(h1)),
                             l2 = f2bf(r.z - bf2f(h2)), l3 = f2bf(r.w - bf2f(h3));
        *(ushort4*)(hhi + (size_t)v * 256 + lane * 4) = make_ushort4(h0, h1, h2, h3);
        *(ushort4*)(hlo + (size_t)v * 256 + lane * 4) = make_ushort4(l0, l1, l2, l3);
    }
    if (W2) {  // fused layer-3 row-dot: sv[v] = dot(h2[v,:], W2)
        const float4 w4 = *(const float4*)(W2 + lane * 4);
        float p = r.x * w4.x + r.y * w4.y + r.z * w4.z + r.w * w4.w;
        for (int ofs = 32; ofs > 0; ofs >>= 1) p += __shfl_down(p, ofs, 64);
        if (lane == 0) sv[v] = p;
    }

    // partial logits: pl[v][c] (+)= sum_j h[col0+j] * Wc[col0+j][c]
    const float* __restrict__ wcp = Wc + (size_t)(col0 + lane * 4) * 10;
    float pc[10];
#pragma unroll
    for (int c = 0; c < 10; c++)
        pc[c] = r.x * wcp[c] + r.y * wcp[10 + c] + r.z * wcp[20 + c] + r.w * wcp[30 + c];
#pragma unroll
    for (int c = 0; c < 10; c++) {
        float q = pc[c];
        for (int ofs = 32; ofs > 0; ofs >>= 1) q += __shfl_down(q, ofs, 64);
        if (lane == 0) {
            float* dp = pl + (size_t)v * 10 + c;
            *dp = accum ? (*dp + q) : q;
        }
    }
}

// ---------------- layer-3 scalar aggregate + logits finalize + h3 pair scatter ----------------
__global__ void k_agg_scalar(const float* __restrict__ sv, const float* __restrict__ b2,
                             const int* __restrict__ deg_d,
                             const int* __restrict__ offD, const int2* __restrict__ csrD_sw,
                             const int* __restrict__ csrD_eid,
                             const int* __restrict__ offS, const int* __restrict__ csrS_eid,
                             const float* __restrict__ Wc, const float* __restrict__ bc,
                             const float* __restrict__ pl,
                             float* __restrict__ nf, float* __restrict__ pairs,
                             float* __restrict__ logits, int n) {
    const int v = blockIdx.x * blockDim.x + threadIdx.x;
    if (v >= n) return;
    const float dii = 1.0f / (float)(deg_d[v] + 1);
    float acc = dii * sv[v];
    const int d0 = offD[v], d1 = offD[v + 1];
    int2 pk = (d0 < d1) ? csrD_sw[d0] : make_int2(0, 0);
    for (int idx = d0; idx < d1; idx++) {
        const int2 nk = (idx + 1 < d1) ? csrD_sw[idx + 1] : make_int2(0, 0);
        acc += __int_as_float(pk.y) * sv[pk.x];
        pk = nk;
    }
    const float h3 = tanhf(acc + b2[0]);
    nf[(size_t)v * 513 + 512] = h3;
#pragma unroll
    for (int c = 0; c < 10; c++)
        logits[(size_t)v * 10 + c] = pl[(size_t)v * 10 + c] + h3 * Wc[5120 + c] + bc[c];
    const int so1 = offS[v + 1];
    for (int j = offS[v]; j < so1; j++)
        __builtin_nontemporal_store(h3, pairs + (size_t)csrS_eid[j] * 1026 + 512);
    for (int j = d0; j < d1; j++)
        __builtin_nontemporal_store(h3, pairs + (size_t)csrD_eid[j] * 1026 + 1025);
}

extern "C" void kernel_launch(void* const* d_in, const int* in_sizes, int n_in,
                              void* d_out, int out_size, void* d_ws, size_t ws_size,
                              hipStream_t stream) {
    const float* x  = (const float*)d_in[0];
    const int*   ei = (const int*)d_in[1];
    const float* W0 = (const float*)d_in[2];
    const float* b0 = (const float*)d_in[3];
    const float* W1 = (const float*)d_in[4];
    const float* b1 = (const float*)d_in[5];
    const float* W2 = (const float*)d_in[6];
    const float* b2 = (const float*)d_in[7];
    const float* Wc = (const float*)d_in[8];
    const float* bc = (const float*)d_in[9];

    const int n = in_sizes[0] / 768;   // 20000
    const int e = in_sizes[1] / 2;     // 160000
    const int* src  = ei;
    const int* dstp = ei + e;

    float* out    = (float*)d_out;
    float* logits = out;
    float* nf     = out + (size_t)n * 10;
    float* pairs  = nf + (size_t)n * 513;

    char* w = (char*)d_ws;
    auto alloc = [&](size_t bytes) { char* p = w; w += (bytes + 255) & ~(size_t)255; return p; };
    int*   deg2     = (int*)alloc((size_t)2 * n * 4);  // [deg_d | deg_s], one memset
    int*   deg_d    = deg2;
    int*   deg_s    = deg2 + n;
    int*   off_d    = (int*)alloc((size_t)(n + 1) * 4);
    int*   off_s    = (int*)alloc((size_t)(n + 1) * 4);
    int*   rank_d   = (int*)alloc((size_t)e * 4);
    int*   rank_s   = (int*)alloc((size_t)e * 4);
    int2*  csrD_sw  = (int2*)alloc((size_t)e * 8);
    int*   csrD_eid = (int*)alloc((size_t)e * 4);
    int*   csrS_eid = (int*)alloc((size_t)e * 4);
    unsigned short* w0thi = (unsigned short*)alloc((size_t)256 * 768 * 2);
    unsigned short* w0tlo = (unsigned short*)alloc((size_t)256 * 768 * 2);
    unsigned short* w1thi = (unsigned short*)alloc((size_t)256 * 256 * 2);
    unsigned short* w1tlo = (unsigned short*)alloc((size_t)256 * 256 * 2);
    float* t   = (float*)alloc((size_t)n * 256 * 4);
    unsigned short* hhi = (unsigned short*)alloc((size_t)n * 256 * 2);
    unsigned short* hlo = (unsigned short*)alloc((size_t)n * 256 * 2);
    float* sv  = (float*)alloc((size_t)n * 4);
    float* pl  = (float*)alloc((size_t)n * 10 * 4);

    hipMemsetAsync(deg2, 0, (size_t)2 * n * 4, stream);

    // CSR build, both directions (rank recorded in hist pass)
    k_hist2<<<(e + 255) / 256, 256, 0, stream>>>(src, dstp, deg_d, deg_s, rank_d, rank_s, e);
    k_scan2<<<1, 1024, 0, stream>>>(deg_d, off_d, deg_s, off_s, n, e);
    k_scatter2<<<(e + 255) / 256, 256, 0, stream>>>(src, dstp, deg_d, off_d, off_s,
                                                    rank_d, rank_s, csrD_sw,
                                                    csrD_eid, csrS_eid, e);

    // bf16 hi/lo splits for both weight matrices, one launch
    k_split_wt2<<<(768 * 256 + 256 * 256 + 255) / 256, 256, 0, stream>>>(
        W0, w0thi, w0tlo, W1, w1thi, w1tlo);

    const int strips = (n + 63) / 64;          // 313
    const int per = (strips + 7) / 8;          // strips per XCD chunk
    const int gblocks = 8 * per * 4;

    // layer 1: t = x @ W0 (fused-split MFMA); h1 = tanh(agg(t)+b0); scatter nf/pairs; pl =
    k_gemm64<true><<<gblocks, 256, 0, stream>>>(x, 768, nullptr, nullptr,
                                                w0thi, w0tlo, t, n, 768, per);
    k_aggregate<<<(n + 3) / 4, 256, 0, stream>>>(t, b0, deg_d, off_d, csrD_sw, csrD_eid,
                                                 off_s, csrS_eid, nf, pairs, 0,
                                                 hhi, hlo, nullptr, nullptr, Wc, pl, 0, n);

    // layer 2: t = h1 @ W1; h2 = tanh(agg(t)+b1); scatter; pl +=; fused sv = h2 @ W2
    k_gemm64<false><<<gblocks, 256, 0, stream>>>(nullptr, 0, hhi, hlo,
                                                 w1thi, w1tlo, t, n, 256, per);
    k_aggregate<<<(n + 3) / 4, 256, 0, stream>>>(t, b1, deg_d, off_d, csrD_sw, csrD_eid,
                                                 off_s, csrS_eid, nf, pairs, 256,
                                                 nullptr, nullptr, W2, sv, Wc, pl, 1, n);

    // layer 3 + logits finalize + h3 pair scatter
    k_agg_scalar<<<(n + 255) / 256, 256, 0, stream>>>(sv, b2, deg_d, off_d, csrD_sw,
                                                      csrD_eid, off_s, csrS_eid, Wc, bc, pl,
                                                      nf, pairs, logits, n);
}